// Round 6
// baseline (50.820 us; speedup 1.0000x reference)
//
#include <hip/hip_runtime.h>

// Shapes fixed by the reference: B=1, S=4096, H=32, D=128, M=4096.
#define HH 32
#define DD 128
#define MM 4096
#define ROW_F4 1024          // H*D/4 float4 per token row
#define D_F4   32            // D/4 float4 per (h, m) row

typedef float v4f __attribute__((ext_vector_type(4)));

struct RowCtx {
    int m, s;
    const v4f*  src;    // token row base when s>=0
    const v4f*  cin;    // cache-in base (copy path)
    v4f*        cout;
    const float* sin_;
    float*       sout;
};

__device__ __forceinline__ RowCtx make_row(int r, int cpm, int S,
    const float* kin, const float* vin,
    const float* kc_in, const float* vc_in,
    const float* ksc_in, const float* vsc_in,
    float* kc_out, float* vc_out, float* ksc_out, float* vsc_out)
{
    RowCtx R;
    R.m = r >> 1;
    const int isV = r & 1;
    int s0 = R.m - cpm; if (s0 < 0) s0 += MM;
    R.s = (s0 < S) ? (s0 + MM * ((S - 1 - s0) / MM)) : -1;
    R.src  = (R.s >= 0)
           ? reinterpret_cast<const v4f*>(isV ? vin : kin) + (size_t)R.s * ROW_F4
           : nullptr;
    R.cin  = reinterpret_cast<const v4f*>(isV ? vc_in : kc_in);
    R.cout = reinterpret_cast<v4f*>(isV ? vc_out : kc_out);
    R.sin_ = isV ? vsc_in  : ksc_in;
    R.sout = isV ? vsc_out : ksc_out;
    return R;
}

__device__ __forceinline__ void row_load(v4f (&a)[16], const RowCtx& R, int lane)
{
    if (R.s >= 0) {
        #pragma unroll
        for (int c = 0; c < 16; ++c) a[c] = R.src[c * 64 + lane];
    } else {
        #pragma unroll
        for (int c = 0; c < 16; ++c) {
            int f4 = c * 64 + lane;
            a[c] = R.cin[(f4 >> 5) * (MM * D_F4) + R.m * D_F4 + (f4 & 31)];
        }
    }
}

__device__ __forceinline__ void row_proc(v4f (&a)[16], const RowCtx& R, int lane,
                                         const float* __restrict__ unc)
{
    if (R.s >= 0) {
        float am = 0.0f;
        #pragma unroll
        for (int c = 0; c < 16; ++c)
            am = fmaxf(am, fmaxf(fmaxf(fabsf(a[c].x), fabsf(a[c].y)),
                                 fmaxf(fabsf(a[c].z), fabsf(a[c].w))));
        #pragma unroll
        for (int off = 32; off > 0; off >>= 1)
            am = fmaxf(am, __shfl_xor(am, off, 64));
        const float u   = unc[R.s];
        const float div = (u > 0.1f) ? 224.0f : 448.0f;
        const float sc  = fmaxf(am / div, 1e-8f);
        const float rr  = 1.0f / sc;   // correctly-rounded; <=1ulp vs per-elem div
        #pragma unroll
        for (int c = 0; c < 16; ++c) {
            int f4 = c * 64 + lane;
            int o  = (f4 >> 5) * (MM * D_F4) + R.m * D_F4 + (f4 & 31);
            v4f q;
            q.x = fminf(fmaxf(a[c].x * rr, -448.0f), 448.0f);
            q.y = fminf(fmaxf(a[c].y * rr, -448.0f), 448.0f);
            q.z = fminf(fmaxf(a[c].z * rr, -448.0f), 448.0f);
            q.w = fminf(fmaxf(a[c].w * rr, -448.0f), 448.0f);
            R.cout[o] = q;
        }
        if (lane < HH) R.sout[lane * MM + R.m] = sc;
    } else {
        #pragma unroll
        for (int c = 0; c < 16; ++c) {
            int f4 = c * 64 + lane;
            int o  = (f4 >> 5) * (MM * D_F4) + R.m * D_F4 + (f4 & 31);
            R.cout[o] = a[c];
        }
        if (lane < HH) R.sout[lane * MM + R.m] = R.sin_[lane * MM + R.m];
    }
}

// Persistent 2-deep pipelined kernel: each wave owns 4 rows (2 positions x K/V),
// rotating two register buffers so every steady-state step issues 16 stores AND
// 16 loads (continuous mixed HBM traffic, no convoy phases, no one-generation
// drain). __launch_bounds__(64,2) licenses up to 256 VGPR so the staged row
// stays in registers (R0-R5: allocator targeted high occupancy and
// rematerialized the loads -> double-read + serialized store phase).
__global__ __launch_bounds__(64, 2)
void teleport_quant_kernel(const float* __restrict__ kin,
                           const float* __restrict__ vin,
                           const float* __restrict__ unc,
                           const float* __restrict__ kc_in,
                           const float* __restrict__ vc_in,
                           const float* __restrict__ ksc_in,
                           const float* __restrict__ vsc_in,
                           const int*   __restrict__ cur_pos,
                           float* __restrict__ kc_out,
                           float* __restrict__ vc_out,
                           float* __restrict__ ksc_out,
                           float* __restrict__ vsc_out,
                           int S)
{
    const int lane = threadIdx.x;      // 0..63
    const int w    = blockIdx.x;       // 0..2047

    int cp  = *cur_pos;
    int cpm = cp % MM; if (cpm < 0) cpm += MM;

    const RowCtx R0 = make_row(4 * w + 0, cpm, S, kin, vin, kc_in, vc_in,
                               ksc_in, vsc_in, kc_out, vc_out, ksc_out, vsc_out);
    const RowCtx R1 = make_row(4 * w + 1, cpm, S, kin, vin, kc_in, vc_in,
                               ksc_in, vsc_in, kc_out, vc_out, ksc_out, vsc_out);
    const RowCtx R2 = make_row(4 * w + 2, cpm, S, kin, vin, kc_in, vc_in,
                               ksc_in, vsc_in, kc_out, vc_out, ksc_out, vsc_out);
    const RowCtx R3 = make_row(4 * w + 3, cpm, S, kin, vin, kc_in, vc_in,
                               ksc_in, vsc_in, kc_out, vc_out, ksc_out, vsc_out);

    v4f A[16], B[16];
    row_load(A, R0, lane);
    row_load(B, R1, lane);
    row_proc(A, R0, lane, unc);
    row_load(A, R2, lane);
    row_proc(B, R1, lane, unc);
    row_load(B, R3, lane);
    row_proc(A, R2, lane, unc);
    row_proc(B, R3, lane, unc);
}

extern "C" void kernel_launch(void* const* d_in, const int* in_sizes, int n_in,
                              void* d_out, int out_size, void* d_ws, size_t ws_size,
                              hipStream_t stream) {
    const float* kin = (const float*)d_in[0];
    const float* vin = (const float*)d_in[1];
    const float* unc = (const float*)d_in[2];
    const float* kc  = (const float*)d_in[3];
    const float* vc  = (const float*)d_in[4];
    const float* ksc = (const float*)d_in[5];
    const float* vsc = (const float*)d_in[6];
    const int*   cp  = (const int*)d_in[7];
    const int S = in_sizes[2];   // B*S with B=1

    float* out  = (float*)d_out;
    float* kco  = out;
    float* vco  = kco + (size_t)HH * MM * DD;
    float* ksco = vco + (size_t)HH * MM * DD;
    float* vsco = ksco + (size_t)HH * MM;

    // 2*MM rows, 4 rows per wave, 1 wave per block.
    teleport_quant_kernel<<<(2 * MM) / 4, 64, 0, stream>>>(
        kin, vin, unc, kc, vc, ksc, vsc, cp, kco, vco, ksco, vsco, S);
}